// Round 1
// 174.215 us; speedup vs baseline: 1.0325x; 1.0325x over previous
//
#include <hip/hip_runtime.h>

// MultiHeadAttention: out = softmax((XWq^T)(XWk^T)^T / 8) (XWv^T) Wo^T
// B=2, L=2048, DIM=1024, H=16, D=64. fp32 in/out, bf16 MFMA compute.
//
// R12: attn6 -> attn7. Theory: attn6 was LDS-read-throughput bound (every
//      wave re-read the full 16KB K + 16KB V tile per iter; 8 MB/CU of
//      ds_read_b128 ~= the whole 46us at measured LDS BW, vs a 16.6us MFMA
//      floor). attn7 gives each wave TWO q-row sets (32 rows): each K/V
//      fragment is loaded from LDS once and feeds both sets -> LDS bytes
//      per FLOP halved. Block 256 thr (4 waves x 32 rows = same 128
//      rows/block), grid stays 512; staging/swizzle layouts unchanged.
//      GEMMs unchanged from R11.

#define DIMN 1024
#define NH 16
#define HD 64
#define BB 2
#define LL 2048

typedef float f32x4 __attribute__((ext_vector_type(4)));
typedef short s16x8 __attribute__((ext_vector_type(8)));

#define QSCALE 0.18033688011112042f  // log2(e)/8, folds softmax exp2 domain

static __device__ __forceinline__ unsigned short f2bf(float f) {
  unsigned u = __float_as_uint(f);
  u += 0x7fffu + ((u >> 16) & 1u);   // RNE
  return (unsigned short)(u >> 16);
}
static __device__ __forceinline__ unsigned packbf2(float lo, float hi) {
  return (unsigned)f2bf(lo) | ((unsigned)f2bf(hi) << 16);
}
static __device__ __forceinline__ float xexp2(float x) {
#if __has_builtin(__builtin_amdgcn_exp2f)
  return __builtin_amdgcn_exp2f(x);
#else
  return exp2f(x);
#endif
}
static __device__ __forceinline__ s16x8 cvt8(float4 a, float4 b) {
  s16x8 r;
  r[0] = (short)f2bf(a.x); r[1] = (short)f2bf(a.y);
  r[2] = (short)f2bf(a.z); r[3] = (short)f2bf(a.w);
  r[4] = (short)f2bf(b.x); r[5] = (short)f2bf(b.y);
  r[6] = (short)f2bf(b.z); r[7] = (short)f2bf(b.w);
  return r;
}
// async global->LDS, 16B/lane; LDS dest is wave-uniform base + lane*16
static __device__ __forceinline__ void gld16(const unsigned short* g,
                                             unsigned short* l) {
#if __has_builtin(__builtin_amdgcn_global_load_lds)
  __builtin_amdgcn_global_load_lds(
      (const __attribute__((address_space(1))) void*)g,
      (__attribute__((address_space(3))) void*)l, 16, 0, 0);
#else
  ((uint4*)l)[threadIdx.x & 63] = ((const uint4*)g)[0];
#endif
}

// V storage permutation within each 128-seq group (bits of s):
// pos = b6*64 + b5*32 + (bits3:2)*8 + bit4*4 + bits1:0  — keeps low 2 bits.
static __device__ __forceinline__ int vpos(int s128) {
  return (s128 & 0x60) | ((s128 & 0x0C) << 1) | ((s128 & 0x10) >> 2) | (s128 & 3);
}

// ---------------- fp32 -> bf16 pre-convert (X + 4 weights) ----------------
__global__ __launch_bounds__(256) void cvt_all(
    const float* __restrict__ X, const float* __restrict__ Wq,
    const float* __restrict__ Wk, const float* __restrict__ Wv,
    const float* __restrict__ Wo, unsigned short* __restrict__ out) {
  const int blk = blockIdx.x;
  const float* src;
  unsigned short* dst;
  size_t off;
  if (blk < 2048) {
    src = X; dst = out; off = (size_t)blk * 2048;
  } else {
    int s = (blk - 2048) >> 9;
    src = (s == 0) ? Wq : (s == 1) ? Wk : (s == 2) ? Wv : Wo;
    dst = out + ((size_t)1 << 22) + (size_t)s * (1u << 20);
    off = (size_t)((blk - 2048) & 511) * 2048;
  }
  size_t i = off + (size_t)threadIdx.x * 8;
  float4 v0 = *(const float4*)(src + i);
  float4 v1 = *(const float4*)(src + i + 4);
  uint4 o;
  o.x = packbf2(v0.x, v0.y); o.y = packbf2(v0.z, v0.w);
  o.z = packbf2(v1.x, v1.y); o.w = packbf2(v1.z, v1.w);
  *(uint4*)(dst + i) = o;
}

// ---------------- fused QKV projection, 128x128, BK=64 ----------------
// grid 768 (1D, XCD-swizzled). Rows in LDS are 64 shorts (128 B), chunk-
// swizzled: phys slot p of row r holds logical chunk p ^ (r&7).
__global__ __launch_bounds__(256) void gemm_qkv(
    const unsigned short* __restrict__ Xb, const unsigned short* __restrict__ Wb,
    unsigned short* __restrict__ Qb, unsigned short* __restrict__ Kb,
    unsigned short* __restrict__ VT) {
  __shared__ __align__(16) unsigned short Al[128 * 64];   // 16 KB
  __shared__ __align__(16) unsigned short Bl[128 * 64];   // 16 KB
  const int lin = blockIdx.x;
  const int xcd = lin & 7, sblk = lin >> 3;       // sblk 0..95
  const int m0 = ((xcd & 3) * 8 + (sblk & 7)) * 128;
  const int n0g = ((xcd >> 2) * 12 + (sblk >> 3)) * 128;
  const int sel = n0g >> 10;
  const int tid = threadIdx.x;
  const int w = tid >> 6, lane = tid & 63;
  const int c = lane & 15, quad = lane >> 4;
  const int wm = (w & 1) * 64, wn = (w >> 1) * 64;

  f32x4 zero = {0.f, 0.f, 0.f, 0.f};
  f32x4 acc[4][4];
#pragma unroll
  for (int i = 0; i < 4; ++i)
#pragma unroll
    for (int j = 0; j < 4; ++j) acc[i][j] = zero;

  // staging: wave covers 8 rows per gld16 (8 lanes x 16B per row);
  // source column carries the chunk swizzle (attn K pattern).
  const int l8 = lane >> 3, p8 = lane & 7;
  const unsigned short* gA = Xb + (size_t)(m0 + w * 8 + l8) * DIMN + ((p8 ^ l8) * 8);
  const unsigned short* gB = Wb + (size_t)(n0g + w * 8 + l8) * DIMN + ((p8 ^ l8) * 8);
  unsigned short* lA = Al + (w * 8) * 64;
  unsigned short* lB = Bl + (w * 8) * 64;
  const int c7 = c & 7;

  for (int k0 = 0; k0 < DIMN; k0 += 64) {
    __syncthreads();
#pragma unroll
    for (int r = 0; r < 4; ++r) {
      gld16(gA + k0 + (size_t)(r * 32) * DIMN, lA + r * 32 * 64);
      gld16(gB + k0 + (size_t)(r * 32) * DIMN, lB + r * 32 * 64);
    }
    __syncthreads();
#pragma unroll
    for (int f = 0; f < 2; ++f) {
      const int rd = ((f * 4 + quad) ^ c7) * 8;
      s16x8 a[4], b[4];
#pragma unroll
      for (int i = 0; i < 4; ++i)
        a[i] = *(const s16x8*)&Al[(wm + i * 16 + c) * 64 + rd];
#pragma unroll
      for (int j = 0; j < 4; ++j)
        b[j] = *(const s16x8*)&Bl[(wn + j * 16 + c) * 64 + rd];
      if (sel != 2) {
#pragma unroll
        for (int i = 0; i < 4; ++i)
#pragma unroll
          for (int j = 0; j < 4; ++j)  // swapped -> C^T (4 consecutive d / lane)
            acc[i][j] = __builtin_amdgcn_mfma_f32_16x16x32_bf16(b[j], a[i], acc[i][j], 0, 0, 0);
      } else {
#pragma unroll
        for (int i = 0; i < 4; ++i)
#pragma unroll
          for (int j = 0; j < 4; ++j)  // normal (4 consecutive seq / lane)
            acc[i][j] = __builtin_amdgcn_mfma_f32_16x16x32_bf16(a[i], b[j], acc[i][j], 0, 0, 0);
      }
    }
  }

  const int n0 = n0g & 1023;
  if (sel != 2) {
    // C^T: row = n (d), col = seq. 8B packed stores, layout [B,H,L,D].
    unsigned short* Out = (sel == 0) ? Qb : Kb;
    const float scale = (sel == 0) ? QSCALE : 1.0f;
    const int bi = (m0 + wm) >> 11;
#pragma unroll
    for (int i = 0; i < 4; ++i) {
      const int li = (m0 + wm + i * 16 + c) & 2047;
#pragma unroll
      for (int j = 0; j < 4; ++j) {
        const int nq = n0 + wn + j * 16 + quad * 4;
        const int h = nq >> 6, d = nq & 63;
        uint2 st;
        st.x = packbf2(acc[i][j][0] * scale, acc[i][j][1] * scale);
        st.y = packbf2(acc[i][j][2] * scale, acc[i][j][3] * scale);
        *(uint2*)&Out[(((size_t)bi * NH + h) * LL + li) * HD + d] = st;
      }
    }
  } else {
    // normal C: row = seq, col = n (d). 8B packed stores, layout [B,H,D,L]
    // with vpos permutation per 128-seq group (keeps low 2 bits -> contiguous).
    const int bi = m0 >> 11;
    const int mlo = m0 & 2047;
#pragma unroll
    for (int i = 0; i < 4; ++i) {
      const int pos = mlo + vpos(wm + i * 16 + quad * 4);
#pragma unroll
      for (int j = 0; j < 4; ++j) {
        const int nv = n0 + wn + j * 16 + c;
        const int h = nv >> 6, d = nv & 63;
        uint2 st;
        st.x = packbf2(acc[i][j][0], acc[i][j][1]);
        st.y = packbf2(acc[i][j][2], acc[i][j][3]);
        *(uint2*)&VT[(((size_t)bi * NH + h) * HD + d) * LL + pos] = st;
      }
    }
  }
}

// ---------------- output projection, 128x64, BK=64 ----------------
// grid 512 (1D, XCD-swizzled). Same swizzled 64-short-row LDS tiles.
__global__ __launch_bounds__(256) void gemm_o(
    const unsigned short* __restrict__ A, const unsigned short* __restrict__ Wob,
    float* __restrict__ Out) {
  __shared__ __align__(16) unsigned short Al[128 * 64];   // 16 KB
  __shared__ __align__(16) unsigned short Bl[64 * 64];    // 8 KB
  const int lin = blockIdx.x;
  const int xcd = lin & 7, sblk = lin >> 3;       // sblk 0..63
  const int m0 = ((sblk >> 4) * 8 + xcd) * 128;
  const int n0 = (sblk & 15) * 64;
  const int tid = threadIdx.x;
  const int w = tid >> 6, lane = tid & 63;
  const int c = lane & 15, quad = lane >> 4;
  const int wm = (w & 1) * 64, wn = (w >> 1) * 32;

  f32x4 zero = {0.f, 0.f, 0.f, 0.f};
  f32x4 acc[4][2];
#pragma unroll
  for (int i = 0; i < 4; ++i)
#pragma unroll
    for (int j = 0; j < 2; ++j) acc[i][j] = zero;

  const int l8 = lane >> 3, p8 = lane & 7;
  const unsigned short* gA = A + (size_t)(m0 + w * 8 + l8) * DIMN + ((p8 ^ l8) * 8);
  const unsigned short* gB = Wob + (size_t)(n0 + w * 8 + l8) * DIMN + ((p8 ^ l8) * 8);
  unsigned short* lA = Al + (w * 8) * 64;
  unsigned short* lB = Bl + (w * 8) * 64;
  const int c7 = c & 7;

  for (int k0 = 0; k0 < DIMN; k0 += 64) {
    __syncthreads();
#pragma unroll
    for (int r = 0; r < 4; ++r)
      gld16(gA + k0 + (size_t)(r * 32) * DIMN, lA + r * 32 * 64);
#pragma unroll
    for (int r = 0; r < 2; ++r)
      gld16(gB + k0 + (size_t)(r * 32) * DIMN, lB + r * 32 * 64);
    __syncthreads();
#pragma unroll
    for (int f = 0; f < 2; ++f) {
      const int rd = ((f * 4 + quad) ^ c7) * 8;
      s16x8 a[4], b[2];
#pragma unroll
      for (int i = 0; i < 4; ++i)
        a[i] = *(const s16x8*)&Al[(wm + i * 16 + c) * 64 + rd];
#pragma unroll
      for (int j = 0; j < 2; ++j)
        b[j] = *(const s16x8*)&Bl[(wn + j * 16 + c) * 64 + rd];
#pragma unroll
      for (int i = 0; i < 4; ++i)
#pragma unroll
        for (int j = 0; j < 2; ++j)
          acc[i][j] = __builtin_amdgcn_mfma_f32_16x16x32_bf16(a[i], b[j], acc[i][j], 0, 0, 0);
    }
  }

#pragma unroll
  for (int i = 0; i < 4; ++i)
#pragma unroll
    for (int j = 0; j < 2; ++j)
#pragma unroll
      for (int r = 0; r < 4; ++r)
        Out[(size_t)(m0 + wm + i * 16 + quad * 4 + r) * DIMN + n0 + wn + j * 16 + c] =
            acc[i][j][r];
}

// ---------------- flash attention, 4 waves x (2 x 16) q-rows ----------------
// R12: each wave owns TWO 16-row q-sets; every K/V LDS fragment read feeds
// both sets (2x MFMA per ds_read_b128) -> per-CU LDS read traffic halved.
// Block 256 thr, grid 512 (same bh/qi mapping), 64 KB LDS, 2 blocks/CU.
__global__ __launch_bounds__(256, 2) void attn7(
    const unsigned short* __restrict__ Qb, const unsigned short* __restrict__ Kb,
    const unsigned short* __restrict__ VT, unsigned short* __restrict__ AO) {
  __shared__ __align__(16) unsigned short Kl[2 * 128 * 64];   // 32 KB
  __shared__ __align__(16) unsigned short Vtl[2 * 64 * 128];  // 32 KB

  const int lin = blockIdx.x;
  const int xcd = lin & 7, sblk = lin >> 3;       // sblk 0..63
  const int bh = (sblk >> 4) * 8 + xcd;
  const int qi = sblk & 15;
  const int tid = threadIdx.x;
  const int w = tid >> 6, lane = tid & 63;
  const int c = lane & 15, quad = lane >> 4;
  const int qa = qi * 128 + w * 16;     // set A rows [qa, qa+16)
  const int qbr = qa + 64;              // set B rows [qa+64, qa+80)

  const unsigned short* Qh = Qb + (size_t)bh * LL * HD;
  const unsigned short* Kh = Kb + (size_t)bh * LL * HD;
  const unsigned short* Vh = VT + (size_t)bh * HD * LL;   // [d][l], permuted

  s16x8 qA0 = *(const s16x8*)(Qh + (size_t)(qa + c) * HD + quad * 8);
  s16x8 qA1 = *(const s16x8*)(Qh + (size_t)(qa + c) * HD + 32 + quad * 8);
  s16x8 qB0 = *(const s16x8*)(Qh + (size_t)(qbr + c) * HD + quad * 8);
  s16x8 qB1 = *(const s16x8*)(Qh + (size_t)(qbr + c) * HD + 32 + quad * 8);

  f32x4 zero = {0.f, 0.f, 0.f, 0.f};
  f32x4 oA[4], oB[4];
  float lsumA = 0.f, lsumB = 0.f;
#pragma unroll
  for (int dc = 0; dc < 4; ++dc) { oA[dc] = zero; oB[dc] = zero; }

  // staging: wave w covers K rows [w*32, w*32+32) and V rows [w*16, w*16+16).
  const int l8 = lane >> 3, p8 = lane & 7;
  const unsigned short* gK = Kh + (size_t)(w * 32 + l8) * HD + ((p8 ^ l8) * 8);
  const int l16 = lane >> 4, p16 = lane & 15;
  const int vr0 = w * 16 + l16;
  const int vr1 = w * 16 + 4 + l16;
  const int vr2 = w * 16 + 8 + l16;
  const int vr3 = w * 16 + 12 + l16;
  const unsigned short* gV0 = Vh + (size_t)vr0 * LL + ((p16 ^ (vr0 & 15)) * 8);
  const unsigned short* gV1 = Vh + (size_t)vr1 * LL + ((p16 ^ (vr1 & 15)) * 8);
  const unsigned short* gV2 = Vh + (size_t)vr2 * LL + ((p16 ^ (vr2 & 15)) * 8);
  const unsigned short* gV3 = Vh + (size_t)vr3 * LL + ((p16 ^ (vr3 & 15)) * 8);

  const int kpa = (quad ^ (c & 7)) * 8;
  const int kpb = ((quad + 4) ^ (c & 7)) * 8;

#define STAGE(buf, k0)                                                        \
  do {                                                                        \
    unsigned short* lK_ = Kl + (buf) * (128 * 64) + (w * 32) * 64;            \
    unsigned short* lV_ = Vtl + (buf) * (64 * 128) + (w * 16) * 128;          \
    gld16(gK + (size_t)(k0) * HD, lK_);                                       \
    gld16(gK + (size_t)((k0) + 8) * HD, lK_ + 8 * 64);                        \
    gld16(gK + (size_t)((k0) + 16) * HD, lK_ + 16 * 64);                      \
    gld16(gK + (size_t)((k0) + 24) * HD, lK_ + 24 * 64);                      \
    gld16(gV0 + (k0), lV_);                                                   \
    gld16(gV1 + (k0), lV_ + 4 * 128);                                         \
    gld16(gV2 + (k0), lV_ + 8 * 128);                                         \
    gld16(gV3 + (k0), lV_ + 12 * 128);                                        \
  } while (0)

  STAGE(0, 0);

  for (int it = 0; it < LL / 128; ++it) {
    __syncthreads();
    if (it + 1 < LL / 128) STAGE((it + 1) & 1, (it + 1) * 128);
    const unsigned short* Kt = Kl + (it & 1) * (128 * 64);
    const unsigned short* Vt = Vtl + (it & 1) * (64 * 128);

#pragma unroll
    for (int g = 0; g < 2; ++g) {
      f32x4 sA[4], sB[4];
#pragma unroll
      for (int t4 = 0; t4 < 4; ++t4) {
        const unsigned short* kr = Kt + ((g * 4 + t4) * 16 + c) * 64;
        s16x8 kfa = *(const s16x8*)(kr + kpa);
        s16x8 kfb = *(const s16x8*)(kr + kpb);
        sA[t4] = __builtin_amdgcn_mfma_f32_16x16x32_bf16(kfa, qA0, zero, 0, 0, 0);
        sA[t4] = __builtin_amdgcn_mfma_f32_16x16x32_bf16(kfb, qA1, sA[t4], 0, 0, 0);
        sB[t4] = __builtin_amdgcn_mfma_f32_16x16x32_bf16(kfa, qB0, zero, 0, 0, 0);
        sB[t4] = __builtin_amdgcn_mfma_f32_16x16x32_bf16(kfb, qB1, sB[t4], 0, 0, 0);
      }
      float pA[4][4], pB[4][4];
      float accA = 0.f, accB = 0.f;
#pragma unroll
      for (int t4 = 0; t4 < 4; ++t4)
#pragma unroll
        for (int r = 0; r < 4; ++r) {
          float eA = xexp2(sA[t4][r]);
          float eB = xexp2(sB[t4][r]);
          pA[t4][r] = eA; accA += eA;
          pB[t4][r] = eB; accB += eB;
        }
      lsumA += accA;
      lsumB += accB;
#pragma unroll
      for (int kh = 0; kh < 2; ++kh) {
        const int kk = g * 2 + kh;
        unsigned puA[4], puB[4];
        puA[0] = __builtin_amdgcn_perm(__float_as_uint(pA[2 * kh][1]),
                                       __float_as_uint(pA[2 * kh][0]), 0x07060302u);
        puA[1] = __builtin_amdgcn_perm(__float_as_uint(pA[2 * kh][3]),
                                       __float_as_uint(pA[2 * kh][2]), 0x07060302u);
        puA[2] = __builtin_amdgcn_perm(__float_as_uint(pA[2 * kh + 1][1]),
                                       __float_as_uint(pA[2 * kh + 1][0]), 0x07060302u);
        puA[3] = __builtin_amdgcn_perm(__float_as_uint(pA[2 * kh + 1][3]),
                                       __float_as_uint(pA[2 * kh + 1][2]), 0x07060302u);
        puB[0] = __builtin_amdgcn_perm(__float_as_uint(pB[2 * kh][1]),
                                       __float_as_uint(pB[2 * kh][0]), 0x07060302u);
        puB[1] = __builtin_amdgcn_perm(__float_as_uint(pB[2 * kh][3]),
                                       __float_as_uint(pB[2 * kh][2]), 0x07060302u);
        puB[2] = __builtin_amdgcn_perm(__float_as_uint(pB[2 * kh + 1][1]),
                                       __float_as_uint(pB[2 * kh + 1][0]), 0x07060302u);
        puB[3] = __builtin_amdgcn_perm(__float_as_uint(pB[2 * kh + 1][3]),
                                       __float_as_uint(pB[2 * kh + 1][2]), 0x07060302u);
        s16x8 pfA = *(const s16x8*)puA;
        s16x8 pfB = *(const s16x8*)puB;
#pragma unroll
        for (int dc = 0; dc < 4; ++dc) {
          s16x8 vf = *(const s16x8*)(Vt + (dc * 16 + c) * 128 + (((kk * 4 + quad) ^ c) * 8));
          oA[dc] = __builtin_amdgcn_mfma_f32_16x16x32_bf16(vf, pfA, oA[dc], 0, 0, 0);
          oB[dc] = __builtin_amdgcn_mfma_f32_16x16x32_bf16(vf, pfB, oB[dc], 0, 0, 0);
        }
      }
    }
  }
#undef STAGE

  const int bi = bh >> 4, h = bh & 15;
  float lA = lsumA;
  lA += __shfl_xor(lA, 16);
  lA += __shfl_xor(lA, 32);
  float invA = 1.0f / lA;
  float lB = lsumB;
  lB += __shfl_xor(lB, 16);
  lB += __shfl_xor(lB, 32);
  float invB = 1.0f / lB;
  unsigned short* dstA = AO + ((size_t)bi * LL + qa + c) * DIMN + h * HD + quad * 4;
  unsigned short* dstB = AO + ((size_t)bi * LL + qbr + c) * DIMN + h * HD + quad * 4;
#pragma unroll
  for (int dc = 0; dc < 4; ++dc) {
    uint2 stA, stB;
    stA.x = packbf2(oA[dc][0] * invA, oA[dc][1] * invA);
    stA.y = packbf2(oA[dc][2] * invA, oA[dc][3] * invA);
    stB.x = packbf2(oB[dc][0] * invB, oB[dc][1] * invB);
    stB.y = packbf2(oB[dc][2] * invB, oB[dc][3] * invB);
    *(uint2*)(dstA + dc * 16) = stA;
    *(uint2*)(dstB + dc * 16) = stB;
  }
}

// ---------------- fp32 fallback path (1-wave GEMMs), ws < 48 MiB ----------------
__global__ __launch_bounds__(64) void qkv_proj_f(
    const float* __restrict__ X, const float* __restrict__ Wq,
    const float* __restrict__ Wk, const float* __restrict__ Wv,
    unsigned short* __restrict__ Qb, unsigned short* __restrict__ Kb,
    unsigned short* __restrict__ VT) {
  const int m0 = blockIdx.x * 64;
  const int n0g = blockIdx.y * 64;
  const int sel = n0g >> 10;
  const int n0 = n0g & 1023;
  const float* W = (sel == 0) ? Wq : (sel == 1) ? Wk : Wv;
  const int lane = threadIdx.x;
  const int c = lane & 15, quad = lane >> 4;

  f32x4 zero = {0.f, 0.f, 0.f, 0.f};
  f32x4 acc[4][4];
#pragma unroll
  for (int i = 0; i < 4; ++i)
#pragma unroll
    for (int j = 0; j < 4; ++j) acc[i][j] = zero;

  const float* ab = X + (size_t)(m0 + c) * DIMN + quad * 8;
  const float* bb = W + (size_t)(n0 + c) * DIMN + quad * 8;

  for (int k0 = 0; k0 < DIMN; k0 += 32) {
    s16x8 a[4], b[4];
#pragma unroll
    for (int i = 0; i < 4; ++i) {
      const float* pp = ab + i * 16 * DIMN + k0;
      a[i] = cvt8(*(const float4*)pp, *(const float4*)(pp + 4));
    }
#pragma unroll
    for (int j = 0; j < 4; ++j) {
      const float* pp = bb + j * 16 * DIMN + k0;
      b[j] = cvt8(*(const float4*)pp, *(const float4*)(pp + 4));
    }
    if (sel != 2) {
#pragma unroll
      for (int i = 0; i < 4; ++i)
#pragma unroll
        for (int j = 0; j < 4; ++j)
          acc[i][j] = __builtin_amdgcn_mfma_f32_16x16x32_bf16(a[i], b[j], acc[i][j], 0, 0, 0);
    } else {
#pragma unroll
      for (int i = 0; i < 4; ++i)
#pragma unroll
        for (int j = 0; j < 4; ++j)
          acc[i][j] = __builtin_amdgcn_mfma_f32_16x16x32_bf16(b[j], a[i], acc[i][j], 0, 0, 0);
    }
  }

  if (sel != 2) {
    unsigned short* Out = (sel == 0) ? Qb : Kb;
    const float scale = (sel == 0) ? QSCALE : 1.0f;
#pragma unroll
    for (int i = 0; i < 4; ++i)
#pragma unroll
      for (int j = 0; j < 4; ++j)
#pragma unroll
        for (int r = 0; r < 4; ++r) {
          int row = m0 + i * 16 + quad * 4 + r;
          int nl = n0 + j * 16 + c;
          int bi = row >> 11, li = row & 2047;
          int h = nl >> 6, d = nl & 63;
          Out[(((size_t)bi * NH + h) * LL + li) * HD + d] = f2bf(acc[i][j][r] * scale);
        }
  } else {
#pragma unroll
    for (int i = 0; i < 4; ++i) {
#pragma unroll
      for (int j = 0; j < 4; ++j)
#pragma unroll
        for (int r = 0; r < 4; ++r) {
          int n = n0 + j * 16 + quad * 4 + r;
          int s128 = (m0 & 64) + i * 16 + c;
          int m = (m0 & ~127) + vpos(s128);
          int h = n >> 6, d = n & 63;
          int bi = m0 >> 11;
          VT[(((size_t)bi * NH + h) * HD + d) * LL + (m & 2047)] = f2bf(acc[i][j][r]);
        }
    }
  }
}

__global__ __launch_bounds__(64) void o_proj_f(
    const unsigned short* __restrict__ A, const float* __restrict__ Wo,
    float* __restrict__ Out) {
  const int m0 = blockIdx.x * 64, n0 = blockIdx.y * 64;
  const int lane = threadIdx.x;
  const int c = lane & 15, quad = lane >> 4;

  f32x4 zero = {0.f, 0.f, 0.f, 0.f};
  f32x4 acc[4][4];
#pragma unroll
  for (int i = 0; i < 4; ++i)
#pragma unroll
    for (int j = 0; j < 4; ++j) acc[i][j] = zero;

  const unsigned short* ab = A + (size_t)(m0 + c) * DIMN + quad * 8;
  const float* bb = Wo + (size_t)(n0 + c) * DIMN + quad * 8;

  for (int k0 = 0; k0 < DIMN; k0 += 32) {
    s16x8 a[4], b[4];
#pragma unroll
    for (int i = 0; i < 4; ++i) a[i] = *(const s16x8*)(ab + i * 16 * DIMN + k0);
#pragma unroll
    for (int j = 0; j < 4; ++j) {
      const float* pp = bb + j * 16 * DIMN + k0;
      b[j] = cvt8(*(const float4*)pp, *(const float4*)(pp + 4));
    }
#pragma unroll
    for (int i = 0; i < 4; ++i)
#pragma unroll
      for (int j = 0; j < 4; ++j)
        acc[i][j] = __builtin_amdgcn_mfma_f32_16x16x32_bf16(a[i], b[j], acc[i][j], 0, 0, 0);
  }

#pragma unroll
  for (int i = 0; i < 4; ++i)
#pragma unroll
    for (int j = 0; j < 4; ++j)
#pragma unroll
      for (int r = 0; r < 4; ++r)
        Out[(size_t)(m0 + i * 16 + quad * 4 + r) * DIMN + n0 + j * 16 + c] = acc[i][j][r];
}

extern "C" void kernel_launch(void* const* d_in, const int* in_sizes, int n_in,
                              void* d_out, int out_size, void* d_ws, size_t ws_size,
                              hipStream_t stream) {
  const float* X = (const float*)d_in[0];
  const float* Wq = (const float*)d_in[1];
  const float* Wk = (const float*)d_in[2];
  const float* Wv = (const float*)d_in[3];
  const float* Wo = (const float*)d_in[4];
  float* Out = (float*)d_out;

  const size_t M1 = (size_t)1 << 20;
  unsigned short* ws16 = (unsigned short*)d_ws;

  if (ws_size >= (size_t)48 * 1024 * 1024) {
    unsigned short* Xb = ws16;            // 4M elems
    unsigned short* Wb = ws16 + 4 * M1;   // 4 x 1M (Wq,Wk,Wv,Wo contiguous)
    unsigned short* Qb = ws16 + 8 * M1;
    unsigned short* Kb = ws16 + 12 * M1;
    unsigned short* VT = ws16 + 16 * M1;
    unsigned short* AO = ws16 + 20 * M1;
    cvt_all<<<4096, 256, 0, stream>>>(X, Wq, Wk, Wv, Wo, ws16);
    gemm_qkv<<<768, 256, 0, stream>>>(Xb, Wb, Qb, Kb, VT);
    attn7<<<512, 256, 0, stream>>>(Qb, Kb, VT, AO);
    gemm_o<<<512, 256, 0, stream>>>(AO, Wb + 3 * M1, Out);
  } else {
    unsigned short* Qb = ws16;
    unsigned short* Kb = ws16 + 4 * M1;
    unsigned short* VT = ws16 + 8 * M1;
    unsigned short* AO = ws16 + 12 * M1;
    qkv_proj_f<<<dim3(64, 48), 64, 0, stream>>>(X, Wq, Wk, Wv, Qb, Kb, VT);
    attn7<<<512, 256, 0, stream>>>(Qb, Kb, VT, AO);
    o_proj_f<<<dim3(64, 16), 64, 0, stream>>>(AO, Wo, Out);
  }
}